// Round 1
// baseline (1454.852 us; speedup 1.0000x reference)
//
#include <hip/hip_runtime.h>
#include <math.h>

// Problem constants (B=2, S=2048, D=1024, H=16, HD=64)
#define B_   2
#define S_   2048
#define D_   1024
#define H_   16
#define HD_  64
#define NROW (B_ * S_)                 // 4096 token rows
#define ND   ((size_t)NROW * D_)       // 4,194,304 elements per (N,D) buffer

// ---------------------------------------------------------------------------
// Generic NT GEMM: C[M x NCOL] = A[M x K] * W[NCOL x K]^T + bias[NCOL]
// 64x64 tile, BK=16, 256 threads, 4x4 accumulators per thread. fp32 baseline.
// ---------------------------------------------------------------------------
__global__ __launch_bounds__(256)
void gemm_nt64(const float* __restrict__ A, const float* __restrict__ W,
               const float* __restrict__ bias, float* __restrict__ C,
               int Kdim, int NCOL) {
    __shared__ __align__(16) float As[16][68];  // [k][m]
    __shared__ __align__(16) float Ws[16][68];  // [k][n]

    const int tid = threadIdx.x;
    const int tr = tid >> 4;        // 0..15
    const int tc = tid & 15;        // 0..15
    const int row0 = blockIdx.y * 64;
    const int col0 = blockIdx.x * 64;

    float acc[4][4] = {};

    const int lr = tid >> 2;          // 0..63
    const int lk = (tid & 3) << 2;    // 0,4,8,12
    const float* Ap = A + (size_t)(row0 + lr) * Kdim + lk;
    const float* Wp = W + (size_t)(col0 + lr) * Kdim + lk;

    for (int k0 = 0; k0 < Kdim; k0 += 16) {
        float4 a4 = *(const float4*)(Ap + k0);
        float4 w4 = *(const float4*)(Wp + k0);
        As[lk + 0][lr] = a4.x; As[lk + 1][lr] = a4.y;
        As[lk + 2][lr] = a4.z; As[lk + 3][lr] = a4.w;
        Ws[lk + 0][lr] = w4.x; Ws[lk + 1][lr] = w4.y;
        Ws[lk + 2][lr] = w4.z; Ws[lk + 3][lr] = w4.w;
        __syncthreads();
        #pragma unroll
        for (int k = 0; k < 16; ++k) {
            float4 av = *(const float4*)&As[k][tr << 2];
            float4 wv = *(const float4*)&Ws[k][tc << 2];
            float aa[4] = {av.x, av.y, av.z, av.w};
            float ww[4] = {wv.x, wv.y, wv.z, wv.w};
            #pragma unroll
            for (int i = 0; i < 4; ++i)
                #pragma unroll
                for (int j = 0; j < 4; ++j)
                    acc[i][j] += aa[i] * ww[j];
        }
        __syncthreads();
    }

    const int cbase = col0 + (tc << 2);
    float4 b4 = *(const float4*)&bias[cbase];
    float bb[4] = {b4.x, b4.y, b4.z, b4.w};
    #pragma unroll
    for (int i = 0; i < 4; ++i) {
        int r = row0 + (tr << 2) + i;
        float4 cv;
        cv.x = acc[i][0] + bb[0];
        cv.y = acc[i][1] + bb[1];
        cv.z = acc[i][2] + bb[2];
        cv.w = acc[i][3] + bb[3];
        *(float4*)&C[(size_t)r * NCOL + cbase] = cv;
    }
}

// ---------------------------------------------------------------------------
// Small projections: li (x @ rel_W[:, :D].T + rel_b), lj (x @ rel_W[:, D:].T),
// gate (sigmoid(x @ gate_W.T + gate_b)). One wave per row, 4 rows per block.
// ---------------------------------------------------------------------------
__global__ __launch_bounds__(256)
void proj_small(const float* __restrict__ x, const float* __restrict__ relW,
                const float* __restrict__ relB, const float* __restrict__ gateW,
                const float* __restrict__ gateB,
                float* __restrict__ li, float* __restrict__ lj,
                float* __restrict__ gate) {
    const int wave = threadIdx.x >> 6;   // 0..3
    const int lane = threadIdx.x & 63;
    const int row  = blockIdx.x * 4 + wave;

    const float* xr = x + (size_t)row * D_;
    float xv[16];
    #pragma unroll
    for (int t = 0; t < 16; ++t) xv[t] = xr[lane + 64 * t];

    for (int c = 0; c < 22; ++c) {
        const float* w;
        if (c < 3)       w = relW + c * (2 * D_);
        else if (c < 6)  w = relW + (c - 3) * (2 * D_) + D_;
        else             w = gateW + (size_t)(c - 6) * D_;
        float s = 0.f;
        #pragma unroll
        for (int t = 0; t < 16; ++t) s += xv[t] * w[lane + 64 * t];
        #pragma unroll
        for (int off = 32; off; off >>= 1) s += __shfl_xor(s, off);
        if (lane == 0) {
            if (c < 3)      li[row * 3 + c] = s + relB[c];
            else if (c < 6) lj[row * 3 + (c - 3)] = s;
            else            gate[row * H_ + (c - 6)] =
                                1.f / (1.f + expf(-(s + gateB[c - 6])));
        }
    }
}

// ---------------------------------------------------------------------------
// Flash attention with relation bias + gate.
// Grid: (S/64, B*H). Block: 256 threads (16x16, 4x4 scores per thread).
// LDS: Qs[d][i], KPs (K as [d][j], then reused as P [j][i]), Vs[j][hd].
// ---------------------------------------------------------------------------
__global__ __launch_bounds__(256)
void flash_attn(const float* __restrict__ Q, const float* __restrict__ K,
                const float* __restrict__ V, const float* __restrict__ li,
                const float* __restrict__ lj, const float* __restrict__ gate,
                const float* __restrict__ logical_bias,
                float* __restrict__ AO) {
    __shared__ __align__(16) float Qs[64][68];   // [d][i]
    __shared__ __align__(16) float KPs[64][68];  // K: [d][j]  /  P: [j][i]
    __shared__ __align__(16) float Vs[64][68];   // [j][hd]
    __shared__ float lis[64][3];
    __shared__ float ljs[64][3];
    __shared__ float gs[64];

    const int tid = threadIdx.x;
    const int bh = blockIdx.y;
    const int b = bh >> 4, h = bh & 15;
    const int i0 = blockIdx.x * 64;
    const size_t rowbase = (size_t)(b * S_ + i0);

    const float lb0 = logical_bias[h * 3 + 0];
    const float lb1 = logical_bias[h * 3 + 1];
    const float lb2 = logical_bias[h * 3 + 2];

    // Load Q tile transposed: Qs[d][i] = Q[(b*S+i0+i)*D + h*64 + d]
    {
        const int i = tid >> 2;
        const int d4 = (tid & 3) << 4;
        const float* qp = Q + (rowbase + i) * D_ + h * 64 + d4;
        #pragma unroll
        for (int u = 0; u < 4; ++u) {
            float4 q4 = *(const float4*)(qp + u * 4);
            int d = d4 + u * 4;
            Qs[d + 0][i] = q4.x; Qs[d + 1][i] = q4.y;
            Qs[d + 2][i] = q4.z; Qs[d + 3][i] = q4.w;
        }
    }
    if (tid < 64) {
        gs[tid] = gate[(rowbase + tid) * H_ + h];
        lis[tid][0] = li[(rowbase + tid) * 3 + 0];
        lis[tid][1] = li[(rowbase + tid) * 3 + 1];
        lis[tid][2] = li[(rowbase + tid) * 3 + 2];
    }

    const int tr = tid >> 4;   // 0..15  (rows 4*tr .. 4*tr+3)
    const int tc = tid & 15;   // 0..15  (cols 4*tc .. 4*tc+3)

    float o[4][4] = {};
    float m_r[4], l_r[4];
    #pragma unroll
    for (int i = 0; i < 4; ++i) { m_r[i] = -1e30f; l_r[i] = 0.f; }

    for (int j0 = 0; j0 < S_; j0 += 64) {
        // Load K transposed and V natural
        {
            const int j = tid >> 2;
            const int d4 = (tid & 3) << 4;
            const size_t jb = (size_t)(b * S_ + j0 + j);
            const float* kp = K + jb * D_ + h * 64 + d4;
            const float* vp = V + jb * D_ + h * 64 + d4;
            #pragma unroll
            for (int u = 0; u < 4; ++u) {
                int d = d4 + u * 4;
                float4 k4 = *(const float4*)(kp + u * 4);
                KPs[d + 0][j] = k4.x; KPs[d + 1][j] = k4.y;
                KPs[d + 2][j] = k4.z; KPs[d + 3][j] = k4.w;
                float4 v4 = *(const float4*)(vp + u * 4);
                *(float4*)&Vs[j][d] = v4;
            }
        }
        if (tid < 64) {
            size_t jb = (size_t)(b * S_ + j0 + tid);
            ljs[tid][0] = lj[jb * 3 + 0];
            ljs[tid][1] = lj[jb * 3 + 1];
            ljs[tid][2] = lj[jb * 3 + 2];
        }
        __syncthreads();

        // Scores: s[i][j] = sum_d Q[i][d] * K[j][d]
        float s[4][4] = {};
        #pragma unroll 8
        for (int d = 0; d < 64; ++d) {
            float4 qa = *(const float4*)&Qs[d][tr << 2];
            float4 kb = *(const float4*)&KPs[d][tc << 2];
            float qq[4] = {qa.x, qa.y, qa.z, qa.w};
            float kk[4] = {kb.x, kb.y, kb.z, kb.w};
            #pragma unroll
            for (int i = 0; i < 4; ++i)
                #pragma unroll
                for (int j = 0; j < 4; ++j)
                    s[i][j] += qq[i] * kk[j];
        }

        // Relation bias + gate: s = s/8 + g_i * softmax3(li+lj) . lb
        #pragma unroll
        for (int i = 0; i < 4; ++i) {
            const int ri = (tr << 2) + i;
            const float g  = gs[ri];
            const float a0 = lis[ri][0], a1 = lis[ri][1], a2 = lis[ri][2];
            #pragma unroll
            for (int j = 0; j < 4; ++j) {
                const int cj = (tc << 2) + j;
                float t0 = a0 + ljs[cj][0];
                float t1 = a1 + ljs[cj][1];
                float t2 = a2 + ljs[cj][2];
                float mx = fmaxf(t0, fmaxf(t1, t2));
                float e0 = expf(t0 - mx), e1 = expf(t1 - mx), e2 = expf(t2 - mx);
                float inv = 1.f / (e0 + e1 + e2);
                float bias = (e0 * lb0 + e1 * lb1 + e2 * lb2) * inv;
                s[i][j] = s[i][j] * 0.125f + g * bias;
            }
        }

        // Online softmax over j (row groups = 16 contiguous lanes)
        float f_r[4];
        #pragma unroll
        for (int i = 0; i < 4; ++i) {
            float mx = fmaxf(fmaxf(s[i][0], s[i][1]), fmaxf(s[i][2], s[i][3]));
            #pragma unroll
            for (int off = 1; off < 16; off <<= 1) mx = fmaxf(mx, __shfl_xor(mx, off));
            float mnew = fmaxf(m_r[i], mx);
            float f = expf(m_r[i] - mnew);
            float rs = 0.f;
            #pragma unroll
            for (int j = 0; j < 4; ++j) {
                float p = expf(s[i][j] - mnew);
                s[i][j] = p;
                rs += p;
            }
            #pragma unroll
            for (int off = 1; off < 16; off <<= 1) rs += __shfl_xor(rs, off);
            l_r[i] = l_r[i] * f + rs;
            m_r[i] = mnew;
            f_r[i] = f;
        }

        __syncthreads();   // everyone done reading KPs as K

        // Write P transposed: P[j][i]
        #pragma unroll
        for (int i = 0; i < 4; ++i)
            #pragma unroll
            for (int j = 0; j < 4; ++j)
                KPs[(tc << 2) + j][(tr << 2) + i] = s[i][j];
        __syncthreads();

        // PV: o[i][c] = o[i][c]*f + sum_j P[j][4tr+i] * V[j][4tc+c]
        #pragma unroll
        for (int i = 0; i < 4; ++i)
            #pragma unroll
            for (int c = 0; c < 4; ++c)
                o[i][c] *= f_r[i];
        #pragma unroll 8
        for (int j = 0; j < 64; ++j) {
            float4 pa = *(const float4*)&KPs[j][tr << 2];
            float4 vb = *(const float4*)&Vs[j][tc << 2];
            float pp[4] = {pa.x, pa.y, pa.z, pa.w};
            float vv[4] = {vb.x, vb.y, vb.z, vb.w};
            #pragma unroll
            for (int i = 0; i < 4; ++i)
                #pragma unroll
                for (int c = 0; c < 4; ++c)
                    o[i][c] += pp[i] * vv[c];
        }
        __syncthreads();   // done with KPs/Vs before next tile's loads
    }

    // Epilogue: normalize and store AO[(b*S+i)*D + h*64 + hd]
    #pragma unroll
    for (int i = 0; i < 4; ++i) {
        float invl = 1.f / l_r[i];
        int r = i0 + (tr << 2) + i;
        float* op = AO + ((size_t)(b * S_ + r)) * D_ + h * 64 + (tc << 2);
        float4 ov;
        ov.x = o[i][0] * invl;
        ov.y = o[i][1] * invl;
        ov.z = o[i][2] * invl;
        ov.w = o[i][3] * invl;
        *(float4*)op = ov;
    }
}

// ---------------------------------------------------------------------------
extern "C" void kernel_launch(void* const* d_in, const int* in_sizes, int n_in,
                              void* d_out, int out_size, void* d_ws, size_t ws_size,
                              hipStream_t stream) {
    const float* x    = (const float*)d_in[0];
    const float* Wq   = (const float*)d_in[1];
    const float* bq   = (const float*)d_in[2];
    const float* Wk   = (const float*)d_in[3];
    const float* bk   = (const float*)d_in[4];
    const float* Wv   = (const float*)d_in[5];
    const float* bv   = (const float*)d_in[6];
    const float* Wo   = (const float*)d_in[7];
    const float* bo   = (const float*)d_in[8];
    const float* relW = (const float*)d_in[9];
    const float* relB = (const float*)d_in[10];
    const float* lb   = (const float*)d_in[11];
    const float* gW   = (const float*)d_in[12];
    const float* gb   = (const float*)d_in[13];

    float* ws  = (float*)d_ws;
    float* Qb  = ws;
    float* Kb  = ws + ND;
    float* Vb  = ws + 2 * ND;
    float* AOb = ws + 3 * ND;
    float* LI  = ws + 4 * ND;
    float* LJ  = LI + (size_t)NROW * 3;
    float* GA  = LJ + (size_t)NROW * 3;

    dim3 gg(D_ / 64, NROW / 64);   // (16, 64)

    gemm_nt64<<<gg, 256, 0, stream>>>(x, Wq, bq, Qb, D_, D_);
    gemm_nt64<<<gg, 256, 0, stream>>>(x, Wk, bk, Kb, D_, D_);
    gemm_nt64<<<gg, 256, 0, stream>>>(x, Wv, bv, Vb, D_, D_);
    proj_small<<<NROW / 4, 256, 0, stream>>>(x, relW, relB, gW, gb, LI, LJ, GA);

    flash_attn<<<dim3(S_ / 64, B_ * H_), 256, 0, stream>>>(
        Qb, Kb, Vb, LI, LJ, GA, lb, AOb);

    gemm_nt64<<<gg, 256, 0, stream>>>(AOb, Wo, bo, (float*)d_out, D_, D_);
}

// Round 2
// 335.109 us; speedup vs baseline: 4.3414x; 4.3414x over previous
//
#include <hip/hip_runtime.h>
#include <math.h>

#define B_   2
#define S_   2048
#define D_   1024
#define H_   16
#define NROW (B_ * S_)

typedef __bf16 bf16_t;
typedef __bf16 bf16x8 __attribute__((ext_vector_type(8)));
typedef __bf16 bf16x4v __attribute__((ext_vector_type(4)));
typedef float  f32x4  __attribute__((ext_vector_type(4)));

#define MFMA16(a, b, c) __builtin_amdgcn_mfma_f32_16x16x32_bf16((a), (b), (c), 0, 0, 0)

__device__ __forceinline__ void glds16(const void* src, void* lds) {
    __builtin_amdgcn_global_load_lds(
        (const __attribute__((address_space(1))) void*)src,
        (__attribute__((address_space(3))) void*)lds, 16, 0, 0);
}

// ---------------------------------------------------------------------------
// fp32 -> bf16 conversion for x and the 4 weight matrices (one fused kernel).
// blocks 0..4095: x (4M elems). blocks 4096..8191: weights (1M each).
// ---------------------------------------------------------------------------
__global__ __launch_bounds__(256)
void cvt_all(const float* __restrict__ x, const float* __restrict__ wq,
             const float* __restrict__ wk, const float* __restrict__ wv,
             const float* __restrict__ wo, bf16_t* __restrict__ xb,
             bf16_t* __restrict__ wqb, bf16_t* __restrict__ wkb,
             bf16_t* __restrict__ wvb, bf16_t* __restrict__ wob) {
    int bid = blockIdx.x;
    const float* src;
    bf16_t* dst;
    int base;
    if (bid < 4096) { src = x; dst = xb; base = bid; }
    else {
        int k = (bid - 4096) >> 10;
        base = (bid - 4096) & 1023;
        src = (k == 0) ? wq : (k == 1) ? wk : (k == 2) ? wv : wo;
        dst = (k == 0) ? wqb : (k == 1) ? wkb : (k == 2) ? wvb : wob;
    }
    int idx = base * 1024 + threadIdx.x * 4;
    float4 v = *(const float4*)&src[idx];
    bf16x4v o;
    o[0] = (bf16_t)v.x; o[1] = (bf16_t)v.y; o[2] = (bf16_t)v.z; o[3] = (bf16_t)v.w;
    *(bf16x4v*)&dst[idx] = o;
}

// ---------------------------------------------------------------------------
// Small projections. Outputs:
//   EA4[row][4] = {exp(li0+rb0), exp(li1+rb1), exp(li2+rb2), pad}
//   EB4[row][4] = {exp(lj0), exp(lj1), exp(lj2), pad}
//   GA [row][H] = sigmoid(x @ gate_W.T + gate_b)
// ---------------------------------------------------------------------------
__global__ __launch_bounds__(256)
void proj_small(const float* __restrict__ x, const float* __restrict__ relW,
                const float* __restrict__ relB, const float* __restrict__ gateW,
                const float* __restrict__ gateB,
                float* __restrict__ EA4, float* __restrict__ EB4,
                float* __restrict__ GA) {
    const int wave = threadIdx.x >> 6;
    const int lane = threadIdx.x & 63;
    const int row  = blockIdx.x * 4 + wave;

    const float* xr = x + (size_t)row * D_;
    float xv[16];
    #pragma unroll
    for (int t = 0; t < 16; ++t) xv[t] = xr[lane + 64 * t];

    for (int c = 0; c < 22; ++c) {
        const float* w;
        if (c < 3)       w = relW + c * (2 * D_);
        else if (c < 6)  w = relW + (c - 3) * (2 * D_) + D_;
        else             w = gateW + (size_t)(c - 6) * D_;
        float s = 0.f;
        #pragma unroll
        for (int t = 0; t < 16; ++t) s += xv[t] * w[lane + 64 * t];
        #pragma unroll
        for (int off = 32; off; off >>= 1) s += __shfl_xor(s, off);
        if (lane == 0) {
            if (c < 3)      EA4[row * 4 + c] = expf(s + relB[c]);
            else if (c < 6) EB4[row * 4 + (c - 3)] = expf(s);
            else            GA[row * H_ + (c - 6)] =
                                1.f / (1.f + expf(-(s + gateB[c - 6])));
        }
    }
}

// ---------------------------------------------------------------------------
// bf16 NT GEMM: C[M x N] = (A[M x K] * W[N x K]^T + bias) * scale
// 128x128 tile, BK=32, 4 waves, 16 MFMA (16x16x32) per K-step.
// global_load_lds (16B) staging; frag reads chunk-swizzled (2-way max).
// ---------------------------------------------------------------------------
template<int OUTBF16>
__global__ __launch_bounds__(256)
void gemm_bf16(const bf16_t* __restrict__ A, const bf16_t* __restrict__ W,
               const float* __restrict__ bias, void* __restrict__ Cout,
               int N, int K, float scale) {
    __shared__ __align__(16) bf16_t As[128 * 32];
    __shared__ __align__(16) bf16_t Bs[128 * 32];

    const int tid = threadIdx.x, w = tid >> 6, l = tid & 63;
    const int row0 = blockIdx.y * 128, col0 = blockIdx.x * 128;
    const int wr = w >> 1, wc = w & 1;
    const int p16 = l & 15, g4 = l >> 4;

    f32x4 acc[4][4];
    #pragma unroll
    for (int i = 0; i < 4; ++i)
        #pragma unroll
        for (int j = 0; j < 4; ++j) acc[i][j] = (f32x4){0.f, 0.f, 0.f, 0.f};

    const int r0 = l >> 2, ch = l & 3;
    const int r1 = 16 + r0;
    const int ca0 = (ch ^ ((r0 >> 1) & 3)) << 3;
    const int ca1 = (ch ^ ((r1 >> 1) & 3)) << 3;
    const bf16_t* aS = A + (size_t)(row0 + w * 32) * K;
    const bf16_t* bS = W + (size_t)(col0 + w * 32) * K;
    bf16_t* aD = As + w * 1024;
    bf16_t* bD = Bs + w * 1024;

    for (int k0 = 0; k0 < K; k0 += 32) {
        glds16(aS + (size_t)r0 * K + k0 + ca0, aD);
        glds16(aS + (size_t)r1 * K + k0 + ca1, aD + 512);
        glds16(bS + (size_t)r0 * K + k0 + ca0, bD);
        glds16(bS + (size_t)r1 * K + k0 + ca1, bD + 512);
        __syncthreads();

        bf16x8 af[4], bfr[4];
        #pragma unroll
        for (int mi = 0; mi < 4; ++mi) {
            int row = wr * 64 + mi * 16 + p16;
            int chk = g4 ^ ((row >> 1) & 3);
            af[mi] = *(const bf16x8*)&As[row * 32 + chk * 8];
        }
        #pragma unroll
        for (int nj = 0; nj < 4; ++nj) {
            int row = wc * 64 + nj * 16 + p16;
            int chk = g4 ^ ((row >> 1) & 3);
            bfr[nj] = *(const bf16x8*)&Bs[row * 32 + chk * 8];
        }
        #pragma unroll
        for (int mi = 0; mi < 4; ++mi)
            #pragma unroll
            for (int nj = 0; nj < 4; ++nj)
                acc[mi][nj] = MFMA16(af[mi], bfr[nj], acc[mi][nj]);
        __syncthreads();
    }

    const int cj = col0 + wc * 64 + p16;
    #pragma unroll
    for (int nj = 0; nj < 4; ++nj) {
        int j = cj + nj * 16;
        float bj = bias[j];
        #pragma unroll
        for (int mi = 0; mi < 4; ++mi) {
            int ib = row0 + wr * 64 + mi * 16 + g4 * 4;
            #pragma unroll
            for (int r = 0; r < 4; ++r) {
                float v = (acc[mi][nj][r] + bj) * scale;
                if (OUTBF16)
                    ((bf16_t*)Cout)[(size_t)(ib + r) * N + j] = (bf16_t)v;
                else
                    ((float*)Cout)[(size_t)(ib + r) * N + j] = v;
            }
        }
    }
}

// ---------------------------------------------------------------------------
// MFMA flash attention with factored relation bias + gate.
// Grid (S/64, B*H), 256 threads = 4 waves; wave w owns Q rows [w*16, w*16+16).
// No online max (scores bounded ~|3|): p = exp(s), normalize at the end.
// ---------------------------------------------------------------------------
__global__ __launch_bounds__(256)
void flash_mfma(const bf16_t* __restrict__ Q, const bf16_t* __restrict__ Kg,
                const bf16_t* __restrict__ Vg, const float4* __restrict__ EA4,
                const float4* __restrict__ EB4, const float* __restrict__ GA,
                const float* __restrict__ LB, bf16_t* __restrict__ AO) {
    __shared__ __align__(16) bf16_t Ks[64 * 64];      // [j][d], src-preswizzled
    __shared__ __align__(16) bf16_t Vt[64 * 64];      // [hd][j], swizzled
    __shared__ __align__(16) bf16_t Ps[4][16 * 64];   // per-wave [i][j], swizzled
    __shared__ __align__(16) float  ebs[64 * 4];

    const int tid = threadIdx.x, w = tid >> 6, l = tid & 63;
    const int b = blockIdx.y >> 4, h = blockIdx.y & 15;
    const int i0 = blockIdx.x * 64;
    const size_t rowb = (size_t)b * S_ + i0;
    const int p16 = l & 15, g4 = l >> 4;

    const float lb0 = LB[h * 3 + 0], lb1 = LB[h * 3 + 1], lb2 = LB[h * 3 + 2];

    // Q A-fragments (held in registers for the whole block)
    bf16x8 qf[2];
    {
        const bf16_t* qp = Q + (rowb + w * 16 + p16) * D_ + h * 64 + g4 * 8;
        qf[0] = *(const bf16x8*)qp;
        qf[1] = *(const bf16x8*)(qp + 32);
    }

    // Per-row bias constants: rows i_loc = g4*4 + r
    float eaR[4][3], cnR[4][3];
    float lsum[4] = {0.f, 0.f, 0.f, 0.f};
    #pragma unroll
    for (int r = 0; r < 4; ++r) {
        size_t gi = rowb + w * 16 + g4 * 4 + r;
        float4 e = EA4[gi];
        float g = GA[gi * H_ + h];
        eaR[r][0] = e.x; eaR[r][1] = e.y; eaR[r][2] = e.z;
        cnR[r][0] = g * e.x * lb0; cnR[r][1] = g * e.y * lb1; cnR[r][2] = g * e.z * lb2;
    }

    f32x4 o[4];
    #pragma unroll
    for (int nb = 0; nb < 4; ++nb) o[nb] = (f32x4){0.f, 0.f, 0.f, 0.f};

    const int vj = tid >> 2, vc = (tid & 3) * 16;   // V-stage mapping
    const int kr0 = l >> 3, kc0 = l & 7;            // K-stage mapping

    for (int j0 = 0; j0 < S_; j0 += 64) {
        const size_t jb = (size_t)b * S_ + j0;
        // --- K stage: global_load_lds with pre-swizzled source column ---
        {
            int rowA = w * 16 + kr0;
            int rowB = rowA + 8;
            glds16(Kg + (jb + rowA) * D_ + h * 64 + ((kc0 ^ (rowA & 7)) << 3),
                   Ks + w * 1024);
            glds16(Kg + (jb + rowB) * D_ + h * 64 + ((kc0 ^ (rowB & 7)) << 3),
                   Ks + w * 1024 + 512);
        }
        // --- V stage: reg -> transposed swizzled LDS ---
        bf16x8 v0, v1;
        {
            const bf16_t* vp = Vg + (jb + vj) * D_ + h * 64 + vc;
            v0 = *(const bf16x8*)vp;
            v1 = *(const bf16x8*)(vp + 8);
        }
        if (tid < 64) *(float4*)&ebs[tid * 4] = EB4[jb + tid];
        #pragma unroll
        for (int u = 0; u < 8; ++u) {
            int hd = vc + u;
            int sw = ((hd & 7) ^ ((hd >> 3) & 7)) << 3;
            Vt[hd * 64 + (vj ^ sw)] = v0[u];
        }
        #pragma unroll
        for (int u = 0; u < 8; ++u) {
            int hd = vc + 8 + u;
            int sw = ((hd & 7) ^ ((hd >> 3) & 7)) << 3;
            Vt[hd * 64 + (vj ^ sw)] = v1[u];
        }
        __syncthreads();

        // --- QK^T ---
        f32x4 s[4];
        #pragma unroll
        for (int nb = 0; nb < 4; ++nb) {
            s[nb] = (f32x4){0.f, 0.f, 0.f, 0.f};
            int row = nb * 16 + p16;
            int sw = row & 7;
            bf16x8 k0v = *(const bf16x8*)&Ks[row * 64 + ((g4    ) ^ sw) * 8];
            bf16x8 k1v = *(const bf16x8*)&Ks[row * 64 + ((g4 + 4) ^ sw) * 8];
            s[nb] = MFMA16(qf[0], k0v, s[nb]);
            s[nb] = MFMA16(qf[1], k1v, s[nb]);
        }

        // --- bias + exp + P write (per-wave LDS region, no barrier needed) ---
        #pragma unroll
        for (int nb = 0; nb < 4; ++nb) {
            float4 eb = *(const float4*)&ebs[(nb * 16 + p16) * 4];
            #pragma unroll
            for (int r = 0; r < 4; ++r) {
                float Nv = cnR[r][0] * eb.x + cnR[r][1] * eb.y + cnR[r][2] * eb.z;
                float Dv = eaR[r][0] * eb.x + eaR[r][1] * eb.y + eaR[r][2] * eb.z;
                float sv = s[nb][r] + Nv * __builtin_amdgcn_rcpf(Dv);
                float p = __expf(sv);
                bf16_t pb = (bf16_t)p;
                lsum[r] += (float)pb;
                int irow = g4 * 4 + r;
                int jcol = nb * 16 + p16;
                Ps[w][irow * 64 + (jcol ^ ((irow & 7) << 3))] = pb;
            }
        }

        // --- PV ---
        bf16x8 pf0, pf1;
        {
            int sw = p16 & 7;
            pf0 = *(const bf16x8*)&Ps[w][p16 * 64 + ((g4    ) ^ sw) * 8];
            pf1 = *(const bf16x8*)&Ps[w][p16 * 64 + ((g4 + 4) ^ sw) * 8];
        }
        #pragma unroll
        for (int nb = 0; nb < 4; ++nb) {
            int vrow = nb * 16 + p16;
            int sw = (vrow & 7) ^ ((vrow >> 3) & 7);
            bf16x8 vf0 = *(const bf16x8*)&Vt[vrow * 64 + ((g4    ) ^ sw) * 8];
            bf16x8 vf1 = *(const bf16x8*)&Vt[vrow * 64 + ((g4 + 4) ^ sw) * 8];
            o[nb] = MFMA16(pf0, vf0, o[nb]);
            o[nb] = MFMA16(pf1, vf1, o[nb]);
        }
        __syncthreads();
    }

    // --- epilogue: row-sum reduce, normalize, store bf16 AO ---
    #pragma unroll
    for (int r = 0; r < 4; ++r) {
        float t = lsum[r];
        t += __shfl_xor(t, 1); t += __shfl_xor(t, 2);
        t += __shfl_xor(t, 4); t += __shfl_xor(t, 8);
        lsum[r] = 1.f / t;
    }
    #pragma unroll
    for (int nb = 0; nb < 4; ++nb)
        #pragma unroll
        for (int r = 0; r < 4; ++r) {
            size_t gi = rowb + w * 16 + g4 * 4 + r;
            AO[gi * D_ + h * 64 + nb * 16 + p16] = (bf16_t)(o[nb][r] * lsum[r]);
        }
}

// ---------------------------------------------------------------------------
extern "C" void kernel_launch(void* const* d_in, const int* in_sizes, int n_in,
                              void* d_out, int out_size, void* d_ws, size_t ws_size,
                              hipStream_t stream) {
    const float* x    = (const float*)d_in[0];
    const float* Wq   = (const float*)d_in[1];
    const float* bq   = (const float*)d_in[2];
    const float* Wk   = (const float*)d_in[3];
    const float* bk   = (const float*)d_in[4];
    const float* Wv   = (const float*)d_in[5];
    const float* bv   = (const float*)d_in[6];
    const float* Wo   = (const float*)d_in[7];
    const float* bo   = (const float*)d_in[8];
    const float* relW = (const float*)d_in[9];
    const float* relB = (const float*)d_in[10];
    const float* lb   = (const float*)d_in[11];
    const float* gW   = (const float*)d_in[12];
    const float* gb   = (const float*)d_in[13];

    uint8_t* W8 = (uint8_t*)d_ws;
    bf16_t* xb  = (bf16_t*)(W8);
    bf16_t* wqb = (bf16_t*)(W8 + (8u  << 20));
    bf16_t* wkb = (bf16_t*)(W8 + (10u << 20));
    bf16_t* wvb = (bf16_t*)(W8 + (12u << 20));
    bf16_t* wob = (bf16_t*)(W8 + (14u << 20));
    bf16_t* Qb  = (bf16_t*)(W8 + (16u << 20));
    bf16_t* Kb  = (bf16_t*)(W8 + (24u << 20));
    bf16_t* Vb  = (bf16_t*)(W8 + (32u << 20));
    bf16_t* AOb = (bf16_t*)(W8 + (40u << 20));
    float*  EA  = (float*)(W8 + (48u << 20));
    float*  EB  = (float*)(W8 + (48u << 20) + NROW * 16);
    float*  GAp = (float*)(W8 + (48u << 20) + NROW * 32);

    cvt_all<<<8192, 256, 0, stream>>>(x, Wq, Wk, Wv, Wo, xb, wqb, wkb, wvb, wob);
    proj_small<<<NROW / 4, 256, 0, stream>>>(x, relW, relB, gW, gb, EA, EB, GAp);

    dim3 gg(D_ / 128, NROW / 128);  // (8, 32)
    gemm_bf16<1><<<gg, 256, 0, stream>>>(xb, wqb, bq, Qb, D_, D_, 0.125f);
    gemm_bf16<1><<<gg, 256, 0, stream>>>(xb, wkb, bk, Kb, D_, D_, 1.f);
    gemm_bf16<1><<<gg, 256, 0, stream>>>(xb, wvb, bv, Vb, D_, D_, 1.f);

    flash_mfma<<<dim3(S_ / 64, B_ * H_), 256, 0, stream>>>(
        Qb, Kb, Vb, (const float4*)EA, (const float4*)EB, GAp, lb, AOb);

    gemm_bf16<0><<<gg, 256, 0, stream>>>(AOb, wob, bo, d_out, D_, D_, 1.f);
}

// Round 3
// 298.172 us; speedup vs baseline: 4.8792x; 1.1239x over previous
//
#include <hip/hip_runtime.h>
#include <math.h>

#define B_   2
#define S_   2048
#define D_   1024
#define H_   16
#define NROW (B_ * S_)
#define L2E_ 1.4426950408889634f

typedef __bf16 bf16_t;
typedef __bf16 bf16x8 __attribute__((ext_vector_type(8)));
typedef __bf16 bf16x4v __attribute__((ext_vector_type(4)));
typedef float  f32x4  __attribute__((ext_vector_type(4)));

#define MFMA16(a, b, c) __builtin_amdgcn_mfma_f32_16x16x32_bf16((a), (b), (c), 0, 0, 0)

#if __has_builtin(__builtin_amdgcn_exp2f)
#define EXP2F(x) __builtin_amdgcn_exp2f(x)
#else
#define EXP2F(x) exp2f(x)
#endif

__device__ __forceinline__ void glds16(const void* src, void* lds) {
    __builtin_amdgcn_global_load_lds(
        (const __attribute__((address_space(1))) void*)src,
        (__attribute__((address_space(3))) void*)lds, 16, 0, 0);
}

// ---------------------------------------------------------------------------
// fp32 -> bf16 conversion for x and the 4 weight matrices.
// ---------------------------------------------------------------------------
__global__ __launch_bounds__(256)
void cvt_all(const float* __restrict__ x, const float* __restrict__ wq,
             const float* __restrict__ wk, const float* __restrict__ wv,
             const float* __restrict__ wo, bf16_t* __restrict__ xb,
             bf16_t* __restrict__ wqb, bf16_t* __restrict__ wkb,
             bf16_t* __restrict__ wvb, bf16_t* __restrict__ wob) {
    int bid = blockIdx.x;
    const float* src;
    bf16_t* dst;
    int base;
    if (bid < 4096) { src = x; dst = xb; base = bid; }
    else {
        int k = (bid - 4096) >> 10;
        base = (bid - 4096) & 1023;
        src = (k == 0) ? wq : (k == 1) ? wk : (k == 2) ? wv : wo;
        dst = (k == 0) ? wqb : (k == 1) ? wkb : (k == 2) ? wvb : wob;
    }
    int idx = base * 1024 + threadIdx.x * 4;
    float4 v = *(const float4*)&src[idx];
    bf16x4v o;
    o[0] = (bf16_t)v.x; o[1] = (bf16_t)v.y; o[2] = (bf16_t)v.z; o[3] = (bf16_t)v.w;
    *(bf16x4v*)&dst[idx] = o;
}

// ---------------------------------------------------------------------------
// Small projections -> EA4 (exp(li+rb)), EB4 (exp(lj)), GA (sigmoid gate).
// ---------------------------------------------------------------------------
__global__ __launch_bounds__(256)
void proj_small(const float* __restrict__ x, const float* __restrict__ relW,
                const float* __restrict__ relB, const float* __restrict__ gateW,
                const float* __restrict__ gateB,
                float* __restrict__ EA4, float* __restrict__ EB4,
                float* __restrict__ GA) {
    const int wave = threadIdx.x >> 6;
    const int lane = threadIdx.x & 63;
    const int row  = blockIdx.x * 4 + wave;

    const float* xr = x + (size_t)row * D_;
    float xv[16];
    #pragma unroll
    for (int t = 0; t < 16; ++t) xv[t] = xr[lane + 64 * t];

    for (int c = 0; c < 22; ++c) {
        const float* w;
        if (c < 3)       w = relW + c * (2 * D_);
        else if (c < 6)  w = relW + (c - 3) * (2 * D_) + D_;
        else             w = gateW + (size_t)(c - 6) * D_;
        float s = 0.f;
        #pragma unroll
        for (int t = 0; t < 16; ++t) s += xv[t] * w[lane + 64 * t];
        #pragma unroll
        for (int off = 32; off; off >>= 1) s += __shfl_xor(s, off);
        if (lane == 0) {
            if (c < 3)      EA4[row * 4 + c] = expf(s + relB[c]);
            else if (c < 6) EB4[row * 4 + (c - 3)] = expf(s);
            else            GA[row * H_ + (c - 6)] =
                                1.f / (1.f + expf(-(s + gateB[c - 6])));
        }
    }
}

// ---------------------------------------------------------------------------
// Shared 128x128 GEMM body, BK=64: C = (A[Mx K] * W[N x K]^T + bias) * scale
// 4 waves; per k-step: 8 glds16 + 32 MFMA per wave. XOR chunk-swizzled LDS.
// ---------------------------------------------------------------------------
__device__ __forceinline__ void gemm_body128(
    const bf16_t* __restrict__ A, const bf16_t* __restrict__ W,
    const float* __restrict__ bias, float scale, int row0, int col0,
    bf16_t* As, bf16_t* Bs, int outbf16, void* Cout, int N, int K)
{
    const int tid = threadIdx.x, w = tid >> 6, l = tid & 63;
    const int wr = w >> 1, wc = w & 1, p16 = l & 15, g4 = l >> 4;

    f32x4 acc[4][4];
    #pragma unroll
    for (int i = 0; i < 4; ++i)
        #pragma unroll
        for (int j = 0; j < 4; ++j) acc[i][j] = (f32x4){0.f, 0.f, 0.f, 0.f};

    const int sr = l >> 3, sc = l & 7;       // staging row-in-8 / chunk
    const bf16_t* aS = A + (size_t)(row0 + w * 32) * K;
    const bf16_t* bS = W + (size_t)(col0 + w * 32) * K;

    for (int k0 = 0; k0 < K; k0 += 64) {
        #pragma unroll
        for (int i = 0; i < 4; ++i) {
            int r = i * 8 + sr;
            int co = k0 + ((sc ^ sr) << 3);
            glds16(aS + (size_t)r * K + co, As + (w * 32 + i * 8) * 64);
            glds16(bS + (size_t)r * K + co, Bs + (w * 32 + i * 8) * 64);
        }
        __syncthreads();
        #pragma unroll
        for (int c = 0; c < 2; ++c) {
            bf16x8 af[4], bfr[4];
            #pragma unroll
            for (int mi = 0; mi < 4; ++mi) {
                int row = wr * 64 + mi * 16 + p16;
                af[mi] = *(const bf16x8*)&As[row * 64 + (((c * 4 + g4) ^ (row & 7)) << 3)];
            }
            #pragma unroll
            for (int nj = 0; nj < 4; ++nj) {
                int row = wc * 64 + nj * 16 + p16;
                bfr[nj] = *(const bf16x8*)&Bs[row * 64 + (((c * 4 + g4) ^ (row & 7)) << 3)];
            }
            #pragma unroll
            for (int mi = 0; mi < 4; ++mi)
                #pragma unroll
                for (int nj = 0; nj < 4; ++nj)
                    acc[mi][nj] = MFMA16(af[mi], bfr[nj], acc[mi][nj]);
        }
        __syncthreads();
    }

    const int cj = col0 + wc * 64 + p16;
    #pragma unroll
    for (int nj = 0; nj < 4; ++nj) {
        int j = cj + nj * 16;
        float bj = bias[j];
        #pragma unroll
        for (int mi = 0; mi < 4; ++mi) {
            int ib = row0 + wr * 64 + mi * 16 + g4 * 4;
            #pragma unroll
            for (int r = 0; r < 4; ++r) {
                float v = (acc[mi][nj][r] + bj) * scale;
                if (outbf16)
                    ((bf16_t*)Cout)[(size_t)(ib + r) * N + j] = (bf16_t)v;
                else
                    ((float*)Cout)[(size_t)(ib + r) * N + j] = v;
            }
        }
    }
}

// Merged Q/K/V projection: grid (24, 32); seg = blockIdx.x>>3 picks W/out.
__global__ __launch_bounds__(256)
void gemm_qkv(const bf16_t* __restrict__ xb,
              const bf16_t* __restrict__ wq, const bf16_t* __restrict__ wk,
              const bf16_t* __restrict__ wv,
              const float* __restrict__ bq, const float* __restrict__ bk,
              const float* __restrict__ bv,
              bf16_t* __restrict__ Qb, bf16_t* __restrict__ Kb,
              bf16_t* __restrict__ Vb) {
    __shared__ __align__(16) bf16_t As[128 * 64];
    __shared__ __align__(16) bf16_t Bs[128 * 64];
    const int seg = blockIdx.x >> 3;
    const int col0 = (blockIdx.x & 7) * 128;
    const int row0 = blockIdx.y * 128;
    const bf16_t* W = (seg == 0) ? wq : (seg == 1) ? wk : wv;
    const float* bias = (seg == 0) ? bq : (seg == 1) ? bk : bv;
    bf16_t* C = (seg == 0) ? Qb : (seg == 1) ? Kb : Vb;
    const float scale = (seg == 0) ? 0.125f * L2E_ : 1.0f;
    gemm_body128(xb, W, bias, scale, row0, col0, As, Bs, 1, C, D_, D_);
}

__global__ __launch_bounds__(256)
void gemm_out(const bf16_t* __restrict__ A, const bf16_t* __restrict__ wo,
              const float* __restrict__ bo, float* __restrict__ out) {
    __shared__ __align__(16) bf16_t As[128 * 64];
    __shared__ __align__(16) bf16_t Bs[128 * 64];
    gemm_body128(A, wo, bo, 1.0f, blockIdx.y * 128, blockIdx.x * 128,
                 As, Bs, 0, out, D_, D_);
}

// ---------------------------------------------------------------------------
// MFMA flash attention. Relation-bias numerator/denominator now computed by
// MFMA (rank-3 outer products), per-element epilogue = fma + rcp + exp2.
// Q pre-scaled by 0.125*log2e; cn pre-scaled by log2e; p = exp2(sv).
// ---------------------------------------------------------------------------
__global__ __launch_bounds__(256)
void flash_mfma(const bf16_t* __restrict__ Q, const bf16_t* __restrict__ Kg,
                const bf16_t* __restrict__ Vg, const float4* __restrict__ EA4,
                const float4* __restrict__ EB4, const float* __restrict__ GA,
                const float* __restrict__ LB, bf16_t* __restrict__ AO) {
    __shared__ __align__(16) bf16_t Ks[64 * 64];      // [j][d], src-preswizzled
    __shared__ __align__(16) bf16_t Vt[64 * 64];      // [hd][j], swizzled
    __shared__ __align__(16) bf16_t Ps[4][16 * 64];   // per-wave [i][j], swizzled
    __shared__ __align__(16) float  ebs[64 * 4];

    const int tid = threadIdx.x, w = tid >> 6, l = tid & 63;
    const int b = blockIdx.y >> 4, h = blockIdx.y & 15;
    const int i0 = blockIdx.x * 64;
    const size_t rowb = (size_t)b * S_ + i0;
    const int p16 = l & 15, g4 = l >> 4;

    const float lb0 = LB[h * 3 + 0], lb1 = LB[h * 3 + 1], lb2 = LB[h * 3 + 2];

    // Q A-fragments (registers for whole block)
    bf16x8 qf[2];
    {
        const bf16_t* qp = Q + (rowb + w * 16 + p16) * D_ + h * 64 + g4 * 8;
        qf[0] = *(const bf16x8*)qp;
        qf[1] = *(const bf16x8*)(qp + 32);
    }

    // Constant A-fragments for the bias MFMAs (row i = p16; k-slots 0..2 on g4==0)
    bf16x8 zer;
    #pragma unroll
    for (int u = 0; u < 8; ++u) zer[u] = (bf16_t)0.f;
    bf16x8 cnf = zer, eaf = zer;
    {
        size_t gi = rowb + w * 16 + p16;
        float4 e = EA4[gi];
        float g = GA[gi * H_ + h] * L2E_;
        if (g4 == 0) {
            cnf[0] = (bf16_t)(g * e.x * lb0);
            cnf[1] = (bf16_t)(g * e.y * lb1);
            cnf[2] = (bf16_t)(g * e.z * lb2);
            eaf[0] = (bf16_t)e.x;
            eaf[1] = (bf16_t)e.y;
            eaf[2] = (bf16_t)e.z;
        }
    }

    float lsum[4] = {0.f, 0.f, 0.f, 0.f};
    f32x4 o[4];
    #pragma unroll
    for (int nb = 0; nb < 4; ++nb) o[nb] = (f32x4){0.f, 0.f, 0.f, 0.f};

    const int vj = tid >> 2, vc = (tid & 3) * 16;   // V-stage mapping
    const int kr0 = l >> 3, kc0 = l & 7;            // K-stage mapping

    for (int j0 = 0; j0 < S_; j0 += 64) {
        const size_t jb = (size_t)b * S_ + j0;
        // --- K stage: global_load_lds with pre-swizzled source column ---
        {
            int rowA = w * 16 + kr0;
            int rowB = rowA + 8;
            glds16(Kg + (jb + rowA) * D_ + h * 64 + ((kc0 ^ (rowA & 7)) << 3),
                   Ks + w * 1024);
            glds16(Kg + (jb + rowB) * D_ + h * 64 + ((kc0 ^ (rowB & 7)) << 3),
                   Ks + w * 1024 + 512);
        }
        // --- V stage: reg -> transposed swizzled LDS ---
        bf16x8 v0, v1;
        {
            const bf16_t* vp = Vg + (jb + vj) * D_ + h * 64 + vc;
            v0 = *(const bf16x8*)vp;
            v1 = *(const bf16x8*)(vp + 8);
        }
        if (tid < 64) *(float4*)&ebs[tid * 4] = EB4[jb + tid];
        #pragma unroll
        for (int u = 0; u < 8; ++u) {
            int hd = vc + u;
            int sw = ((hd & 7) ^ ((hd >> 3) & 7)) << 3;
            Vt[hd * 64 + (vj ^ sw)] = v0[u];
        }
        #pragma unroll
        for (int u = 0; u < 8; ++u) {
            int hd = vc + 8 + u;
            int sw = ((hd & 7) ^ ((hd >> 3) & 7)) << 3;
            Vt[hd * 64 + (vj ^ sw)] = v1[u];
        }
        __syncthreads();

        // --- bias N/D via MFMA (layout matches score fragments) ---
        f32x4 nacc[4], dacc[4];
        #pragma unroll
        for (int nb = 0; nb < 4; ++nb) {
            float4 e = *(const float4*)&ebs[(nb * 16 + p16) * 4];
            bf16x8 ebf = zer;
            if (g4 == 0) {
                ebf[0] = (bf16_t)e.x; ebf[1] = (bf16_t)e.y; ebf[2] = (bf16_t)e.z;
            }
            f32x4 z4 = (f32x4){0.f, 0.f, 0.f, 0.f};
            nacc[nb] = MFMA16(cnf, ebf, z4);
            dacc[nb] = MFMA16(eaf, ebf, z4);
        }

        // --- QK^T ---
        f32x4 s[4];
        #pragma unroll
        for (int nb = 0; nb < 4; ++nb) {
            s[nb] = (f32x4){0.f, 0.f, 0.f, 0.f};
            int row = nb * 16 + p16;
            int sw = row & 7;
            bf16x8 k0v = *(const bf16x8*)&Ks[row * 64 + ((g4    ) ^ sw) * 8];
            bf16x8 k1v = *(const bf16x8*)&Ks[row * 64 + ((g4 + 4) ^ sw) * 8];
            s[nb] = MFMA16(qf[0], k0v, s[nb]);
            s[nb] = MFMA16(qf[1], k1v, s[nb]);
        }

        // --- p = exp2(s + N/D); write P (per-wave LDS region) ---
        #pragma unroll
        for (int nb = 0; nb < 4; ++nb) {
            #pragma unroll
            for (int r = 0; r < 4; ++r) {
                float sv = s[nb][r] + nacc[nb][r] * __builtin_amdgcn_rcpf(dacc[nb][r]);
                float p = EXP2F(sv);
                bf16_t pb = (bf16_t)p;
                lsum[r] += (float)pb;
                int irow = g4 * 4 + r;
                int jcol = nb * 16 + p16;
                Ps[w][irow * 64 + (jcol ^ ((irow & 7) << 3))] = pb;
            }
        }

        // --- PV ---
        bf16x8 pf0, pf1;
        {
            int sw = p16 & 7;
            pf0 = *(const bf16x8*)&Ps[w][p16 * 64 + ((g4    ) ^ sw) * 8];
            pf1 = *(const bf16x8*)&Ps[w][p16 * 64 + ((g4 + 4) ^ sw) * 8];
        }
        #pragma unroll
        for (int nb = 0; nb < 4; ++nb) {
            int vrow = nb * 16 + p16;
            int sw = (vrow & 7) ^ ((vrow >> 3) & 7);
            bf16x8 vf0 = *(const bf16x8*)&Vt[vrow * 64 + ((g4    ) ^ sw) * 8];
            bf16x8 vf1 = *(const bf16x8*)&Vt[vrow * 64 + ((g4 + 4) ^ sw) * 8];
            o[nb] = MFMA16(pf0, vf0, o[nb]);
            o[nb] = MFMA16(pf1, vf1, o[nb]);
        }
        __syncthreads();
    }

    // --- epilogue ---
    #pragma unroll
    for (int r = 0; r < 4; ++r) {
        float t = lsum[r];
        t += __shfl_xor(t, 1); t += __shfl_xor(t, 2);
        t += __shfl_xor(t, 4); t += __shfl_xor(t, 8);
        lsum[r] = 1.f / t;
    }
    #pragma unroll
    for (int nb = 0; nb < 4; ++nb)
        #pragma unroll
        for (int r = 0; r < 4; ++r) {
            size_t gi = rowb + w * 16 + g4 * 4 + r;
            AO[gi * D_ + h * 64 + nb * 16 + p16] = (bf16_t)(o[nb][r] * lsum[r]);
        }
}

// ---------------------------------------------------------------------------
extern "C" void kernel_launch(void* const* d_in, const int* in_sizes, int n_in,
                              void* d_out, int out_size, void* d_ws, size_t ws_size,
                              hipStream_t stream) {
    const float* x    = (const float*)d_in[0];
    const float* Wq   = (const float*)d_in[1];
    const float* bq   = (const float*)d_in[2];
    const float* Wk   = (const float*)d_in[3];
    const float* bk   = (const float*)d_in[4];
    const float* Wv   = (const float*)d_in[5];
    const float* bv   = (const float*)d_in[6];
    const float* Wo   = (const float*)d_in[7];
    const float* bo   = (const float*)d_in[8];
    const float* relW = (const float*)d_in[9];
    const float* relB = (const float*)d_in[10];
    const float* lb   = (const float*)d_in[11];
    const float* gW   = (const float*)d_in[12];
    const float* gb   = (const float*)d_in[13];

    uint8_t* W8 = (uint8_t*)d_ws;
    bf16_t* xb  = (bf16_t*)(W8);
    bf16_t* wqb = (bf16_t*)(W8 + (8u  << 20));
    bf16_t* wkb = (bf16_t*)(W8 + (10u << 20));
    bf16_t* wvb = (bf16_t*)(W8 + (12u << 20));
    bf16_t* wob = (bf16_t*)(W8 + (14u << 20));
    bf16_t* Qb  = (bf16_t*)(W8 + (16u << 20));
    bf16_t* Kb  = (bf16_t*)(W8 + (24u << 20));
    bf16_t* Vb  = (bf16_t*)(W8 + (32u << 20));
    bf16_t* AOb = (bf16_t*)(W8 + (40u << 20));
    float*  EA  = (float*)(W8 + (48u << 20));
    float*  EB  = (float*)(W8 + (48u << 20) + NROW * 16);
    float*  GAp = (float*)(W8 + (48u << 20) + NROW * 32);

    cvt_all<<<8192, 256, 0, stream>>>(x, Wq, Wk, Wv, Wo, xb, wqb, wkb, wvb, wob);
    proj_small<<<NROW / 4, 256, 0, stream>>>(x, relW, relB, gW, gb, EA, EB, GAp);

    gemm_qkv<<<dim3(24, 32), 256, 0, stream>>>(xb, wqb, wkb, wvb, bq, bk, bv,
                                               Qb, Kb, Vb);

    flash_mfma<<<dim3(S_ / 64, B_ * H_), 256, 0, stream>>>(
        Qb, Kb, Vb, (const float4*)EA, (const float4*)EB, GAp, lb, AOb);

    gemm_out<<<dim3(8, 32), 256, 0, stream>>>(AOb, wob, bo, (float*)d_out);
}

// Round 6
// 281.557 us; speedup vs baseline: 5.1672x; 1.0590x over previous
//
#include <hip/hip_runtime.h>
#include <math.h>

#define B_   2
#define S_   2048
#define D_   1024
#define H_   16
#define NROW (B_ * S_)
#define L2E_ 1.4426950408889634f

typedef __bf16 bf16_t;
typedef __bf16 bf16x8 __attribute__((ext_vector_type(8)));
typedef __bf16 bf16x4v __attribute__((ext_vector_type(4)));
typedef float  f32x4  __attribute__((ext_vector_type(4)));

#define MFMA16(a, b, c) __builtin_amdgcn_mfma_f32_16x16x32_bf16((a), (b), (c), 0, 0, 0)

#if __has_builtin(__builtin_amdgcn_exp2f)
#define EXP2F(x) __builtin_amdgcn_exp2f(x)
#else
#define EXP2F(x) exp2f(x)
#endif

__device__ __forceinline__ void glds16(const void* src, void* lds) {
    __builtin_amdgcn_global_load_lds(
        (const __attribute__((address_space(1))) void*)src,
        (__attribute__((address_space(3))) void*)lds, 16, 0, 0);
}

// ---------------------------------------------------------------------------
// fp32 -> bf16 conversion for x and the 4 weight matrices.
// ---------------------------------------------------------------------------
__global__ __launch_bounds__(256)
void cvt_all(const float* __restrict__ x, const float* __restrict__ wq,
             const float* __restrict__ wk, const float* __restrict__ wv,
             const float* __restrict__ wo, bf16_t* __restrict__ xb,
             bf16_t* __restrict__ wqb, bf16_t* __restrict__ wkb,
             bf16_t* __restrict__ wvb, bf16_t* __restrict__ wob) {
    int bid = blockIdx.x;
    const float* src;
    bf16_t* dst;
    int base;
    if (bid < 4096) { src = x; dst = xb; base = bid; }
    else {
        int k = (bid - 4096) >> 10;
        base = (bid - 4096) & 1023;
        src = (k == 0) ? wq : (k == 1) ? wk : (k == 2) ? wv : wo;
        dst = (k == 0) ? wqb : (k == 1) ? wkb : (k == 2) ? wvb : wob;
    }
    int idx = base * 1024 + threadIdx.x * 4;
    float4 v = *(const float4*)&src[idx];
    bf16x4v o;
    o[0] = (bf16_t)v.x; o[1] = (bf16_t)v.y; o[2] = (bf16_t)v.z; o[3] = (bf16_t)v.w;
    *(bf16x4v*)&dst[idx] = o;
}

// ---------------------------------------------------------------------------
// Small projections -> EA4 (exp(li+rb)), EB4 (exp(lj)), GA (sigmoid gate).
// float4-vectorized loads; outputs in float (round-3 format).
// ---------------------------------------------------------------------------
__global__ __launch_bounds__(256)
void proj_small(const float* __restrict__ x, const float* __restrict__ relW,
                const float* __restrict__ relB, const float* __restrict__ gateW,
                const float* __restrict__ gateB,
                float* __restrict__ EA4, float* __restrict__ EB4,
                float* __restrict__ GA) {
    const int wave = threadIdx.x >> 6;
    const int lane = threadIdx.x & 63;
    const int row  = blockIdx.x * 4 + wave;

    const float4* xr = (const float4*)(x + (size_t)row * D_);
    float4 xv[4];
    #pragma unroll
    for (int t = 0; t < 4; ++t) xv[t] = xr[lane + 64 * t];

    for (int c = 0; c < 22; ++c) {
        const float* w;
        if (c < 3)       w = relW + c * (2 * D_);
        else if (c < 6)  w = relW + (c - 3) * (2 * D_) + D_;
        else             w = gateW + (size_t)(c - 6) * D_;
        const float4* w4 = (const float4*)w;
        float s = 0.f;
        #pragma unroll
        for (int t = 0; t < 4; ++t) {
            float4 wv = w4[lane + 64 * t];
            s += xv[t].x * wv.x + xv[t].y * wv.y + xv[t].z * wv.z + xv[t].w * wv.w;
        }
        #pragma unroll
        for (int off = 32; off; off >>= 1) s += __shfl_xor(s, off);
        if (lane == 0) {
            if (c < 3)      EA4[row * 4 + c] = expf(s + relB[c]);
            else if (c < 6) EB4[row * 4 + (c - 3)] = expf(s);
            else            GA[row * H_ + (c - 6)] =
                                1.f / (1.f + expf(-(s + gateB[c - 6])));
        }
    }
}

// ---------------------------------------------------------------------------
// Shared 128x128 GEMM body, BK=64 (unchanged, verified in round 3).
// ---------------------------------------------------------------------------
__device__ __forceinline__ void gemm_body128(
    const bf16_t* __restrict__ A, const bf16_t* __restrict__ W,
    const float* __restrict__ bias, float scale, int row0, int col0,
    bf16_t* As, bf16_t* Bs, int outbf16, void* Cout, int N, int K)
{
    const int tid = threadIdx.x, w = tid >> 6, l = tid & 63;
    const int wr = w >> 1, wc = w & 1, p16 = l & 15, g4 = l >> 4;

    f32x4 acc[4][4];
    #pragma unroll
    for (int i = 0; i < 4; ++i)
        #pragma unroll
        for (int j = 0; j < 4; ++j) acc[i][j] = (f32x4){0.f, 0.f, 0.f, 0.f};

    const int sr = l >> 3, sc = l & 7;
    const bf16_t* aS = A + (size_t)(row0 + w * 32) * K;
    const bf16_t* bS = W + (size_t)(col0 + w * 32) * K;

    for (int k0 = 0; k0 < K; k0 += 64) {
        #pragma unroll
        for (int i = 0; i < 4; ++i) {
            int r = i * 8 + sr;
            int co = k0 + ((sc ^ sr) << 3);
            glds16(aS + (size_t)r * K + co, As + (w * 32 + i * 8) * 64);
            glds16(bS + (size_t)r * K + co, Bs + (w * 32 + i * 8) * 64);
        }
        __syncthreads();
        #pragma unroll
        for (int c = 0; c < 2; ++c) {
            bf16x8 af[4], bfr[4];
            #pragma unroll
            for (int mi = 0; mi < 4; ++mi) {
                int row = wr * 64 + mi * 16 + p16;
                af[mi] = *(const bf16x8*)&As[row * 64 + (((c * 4 + g4) ^ (row & 7)) << 3)];
            }
            #pragma unroll
            for (int nj = 0; nj < 4; ++nj) {
                int row = wc * 64 + nj * 16 + p16;
                bfr[nj] = *(const bf16x8*)&Bs[row * 64 + (((c * 4 + g4) ^ (row & 7)) << 3)];
            }
            #pragma unroll
            for (int mi = 0; mi < 4; ++mi)
                #pragma unroll
                for (int nj = 0; nj < 4; ++nj)
                    acc[mi][nj] = MFMA16(af[mi], bfr[nj], acc[mi][nj]);
        }
        __syncthreads();
    }

    const int cj = col0 + wc * 64 + p16;
    #pragma unroll
    for (int nj = 0; nj < 4; ++nj) {
        int j = cj + nj * 16;
        float bj = bias[j];
        #pragma unroll
        for (int mi = 0; mi < 4; ++mi) {
            int ib = row0 + wr * 64 + mi * 16 + g4 * 4;
            #pragma unroll
            for (int r = 0; r < 4; ++r) {
                float v = (acc[mi][nj][r] + bj) * scale;
                if (outbf16)
                    ((bf16_t*)Cout)[(size_t)(ib + r) * N + j] = (bf16_t)v;
                else
                    ((float*)Cout)[(size_t)(ib + r) * N + j] = v;
            }
        }
    }
}

__global__ __launch_bounds__(256)
void gemm_qkv(const bf16_t* __restrict__ xb,
              const bf16_t* __restrict__ wq, const bf16_t* __restrict__ wk,
              const bf16_t* __restrict__ wv,
              const float* __restrict__ bq, const float* __restrict__ bk,
              const float* __restrict__ bv,
              bf16_t* __restrict__ Qb, bf16_t* __restrict__ Kb,
              bf16_t* __restrict__ Vb) {
    __shared__ __align__(16) bf16_t As[128 * 64];
    __shared__ __align__(16) bf16_t Bs[128 * 64];
    const int seg = blockIdx.x >> 3;
    const int col0 = (blockIdx.x & 7) * 128;
    const int row0 = blockIdx.y * 128;
    const bf16_t* W = (seg == 0) ? wq : (seg == 1) ? wk : wv;
    const float* bias = (seg == 0) ? bq : (seg == 1) ? bk : bv;
    bf16_t* C = (seg == 0) ? Qb : (seg == 1) ? Kb : Vb;
    const float scale = (seg == 0) ? 0.125f * L2E_ : 1.0f;
    gemm_body128(xb, W, bias, scale, row0, col0, As, Bs, 1, C, D_, D_);
}

__global__ __launch_bounds__(256)
void gemm_out(const bf16_t* __restrict__ A, const bf16_t* __restrict__ wo,
              const float* __restrict__ bo, float* __restrict__ out) {
    __shared__ __align__(16) bf16_t As[128 * 64];
    __shared__ __align__(16) bf16_t Bs[128 * 64];
    gemm_body128(A, wo, bo, 1.0f, blockIdx.y * 128, blockIdx.x * 128,
                 As, Bs, 0, out, D_, D_);
}

// ---------------------------------------------------------------------------
// MFMA flash attention — round-3 compute body (verified correct) with a
// double-buffered, async-split schedule:
//   iter t: WRITEV(next, regs from t-1) | STAGEK(next) glds16 | LOADV(t+2)
//           -> compute(cur) -> one barrier.
// K : [j][d] XOR-swizzled via pre-swizzled glds source (per-wave 16 rows)
// V : reg-staged -> transposed+swizzled LDS [hd][j]
// P : per-wave [i][j] swizzled scalar writes, b128 reads
// ---------------------------------------------------------------------------
__global__ __launch_bounds__(256, 3)
void flash_mfma(const bf16_t* __restrict__ Q, const bf16_t* __restrict__ Kg,
                const bf16_t* __restrict__ Vg, const float4* __restrict__ EA4,
                const float4* __restrict__ EB4, const float* __restrict__ GA,
                const float* __restrict__ LB, bf16_t* __restrict__ AO) {
    __shared__ __align__(16) bf16_t Ks[2][4096];   // [j][d], src-preswizzled
    __shared__ __align__(16) bf16_t Vt[2][4096];   // [hd][j], swizzled
    __shared__ __align__(16) bf16_t Ps[4][1024];   // per-wave [i][j], swizzled
    __shared__ __align__(16) float  ebs[2][256];   // 64 rows x float4

    const int tid = threadIdx.x, w = tid >> 6, l = tid & 63;
    const int b = blockIdx.y >> 4, h = blockIdx.y & 15;
    const int i0 = blockIdx.x * 64;
    const size_t rowb = (size_t)b * S_ + i0;
    const int p16 = l & 15, g4 = l >> 4;

    const float lb0 = LB[h * 3 + 0], lb1 = LB[h * 3 + 1], lb2 = LB[h * 3 + 2];

    // Q A-fragments (registers for whole block)
    bf16x8 qf[2];
    {
        const bf16_t* qp = Q + (rowb + w * 16 + p16) * D_ + h * 64 + g4 * 8;
        qf[0] = *(const bf16x8*)qp;
        qf[1] = *(const bf16x8*)(qp + 32);
    }

    // Constant A-fragments for bias MFMAs
    bf16x8 zer;
    #pragma unroll
    for (int u = 0; u < 8; ++u) zer[u] = (bf16_t)0.f;
    bf16x8 cnf = zer, eaf = zer;
    {
        size_t gi = rowb + w * 16 + p16;
        float4 e = EA4[gi];
        float g = GA[gi * H_ + h] * L2E_;
        if (g4 == 0) {
            cnf[0] = (bf16_t)(g * e.x * lb0);
            cnf[1] = (bf16_t)(g * e.y * lb1);
            cnf[2] = (bf16_t)(g * e.z * lb2);
            eaf[0] = (bf16_t)e.x;
            eaf[1] = (bf16_t)e.y;
            eaf[2] = (bf16_t)e.z;
        }
    }

    // --- staging lane mappings ---
    const int vj = tid >> 2, vc = (tid & 3) * 16;   // V: row vj, col chunk vc
    const int kr0 = l >> 3, kc0 = l & 7;            // K glds mapping
    const size_t koff1 = (size_t)(w * 16 + kr0) * D_ + ((kc0 ^ kr0) << 3);
    const size_t koff2 = koff1 + 8 * D_;

    bf16x8 v0, v1;      // in-flight V tile
    float4 ebr;         // in-flight eb row (tid<64)

#define LOADV(jt) do {                                                         \
        const size_t jb0 = (size_t)b * S_ + (jt);                              \
        const bf16_t* vp = Vg + (jb0 + vj) * D_ + h * 64 + vc;                 \
        v0 = *(const bf16x8*)vp;                                               \
        v1 = *(const bf16x8*)(vp + 8);                                         \
        if (tid < 64) ebr = EB4[jb0 + tid];                                    \
    } while (0)

#define WRITEV(buf) do {                                                       \
        _Pragma("unroll")                                                      \
        for (int u = 0; u < 8; ++u) {                                          \
            int hd = vc + u;                                                   \
            int sw = ((hd & 7) ^ ((hd >> 3) & 7)) << 3;                        \
            Vt[buf][hd * 64 + (vj ^ sw)] = v0[u];                              \
        }                                                                      \
        _Pragma("unroll")                                                      \
        for (int u = 0; u < 8; ++u) {                                          \
            int hd = vc + 8 + u;                                               \
            int sw = ((hd & 7) ^ ((hd >> 3) & 7)) << 3;                        \
            Vt[buf][hd * 64 + (vj ^ sw)] = v1[u];                              \
        }                                                                      \
        if (tid < 64) *(float4*)&ebs[buf][tid * 4] = ebr;                      \
    } while (0)

#define STAGEK(buf, jt) do {                                                   \
        const size_t jbase = (size_t)(b * S_ + (jt)) * D_ + h * 64;            \
        glds16(Kg + jbase + koff1, &Ks[buf][w * 1024]);                        \
        glds16(Kg + jbase + koff2, &Ks[buf][w * 1024 + 512]);                  \
    } while (0)

    float lsum[4] = {0.f, 0.f, 0.f, 0.f};
    f32x4 o[4];
    #pragma unroll
    for (int nb = 0; nb < 4; ++nb) o[nb] = (f32x4){0.f, 0.f, 0.f, 0.f};

    // --- prologue: tile 0 into buf 0; tile 1 loads in flight ---
    LOADV(0);
    STAGEK(0, 0);
    WRITEV(0);
    LOADV(64);
    __syncthreads();

    for (int t = 0; t < 32; ++t) {
        const int cur = t & 1;
        if (t < 31) { WRITEV(cur ^ 1); STAGEK(cur ^ 1, (t + 1) * 64); }
        if (t < 30) LOADV((t + 2) * 64);

        // --- bias N/D via MFMA (layout matches score fragments) ---
        f32x4 nacc[4], dacc[4];
        #pragma unroll
        for (int nb = 0; nb < 4; ++nb) {
            float4 e = *(const float4*)&ebs[cur][(nb * 16 + p16) * 4];
            bf16x8 ebf = zer;
            if (g4 == 0) {
                ebf[0] = (bf16_t)e.x; ebf[1] = (bf16_t)e.y; ebf[2] = (bf16_t)e.z;
            }
            f32x4 z4 = (f32x4){0.f, 0.f, 0.f, 0.f};
            nacc[nb] = MFMA16(cnf, ebf, z4);
            dacc[nb] = MFMA16(eaf, ebf, z4);
        }

        // --- QK^T ---
        f32x4 s[4];
        #pragma unroll
        for (int nb = 0; nb < 4; ++nb) {
            s[nb] = (f32x4){0.f, 0.f, 0.f, 0.f};
            int row = nb * 16 + p16;
            int sw = row & 7;
            bf16x8 k0v = *(const bf16x8*)&Ks[cur][row * 64 + ((g4    ) ^ sw) * 8];
            bf16x8 k1v = *(const bf16x8*)&Ks[cur][row * 64 + ((g4 + 4) ^ sw) * 8];
            s[nb] = MFMA16(qf[0], k0v, s[nb]);
            s[nb] = MFMA16(qf[1], k1v, s[nb]);
        }

        // --- p = exp2(s + N/D); write P (per-wave LDS region) ---
        #pragma unroll
        for (int nb = 0; nb < 4; ++nb) {
            #pragma unroll
            for (int r = 0; r < 4; ++r) {
                float sv = s[nb][r] + nacc[nb][r] * __builtin_amdgcn_rcpf(dacc[nb][r]);
                float p = EXP2F(sv);
                bf16_t pb = (bf16_t)p;
                lsum[r] += (float)pb;
                int irow = g4 * 4 + r;
                int jcol = nb * 16 + p16;
                Ps[w][irow * 64 + (jcol ^ ((irow & 7) << 3))] = pb;
            }
        }

        // --- PV ---
        bf16x8 pf0, pf1;
        {
            int sw = p16 & 7;
            pf0 = *(const bf16x8*)&Ps[w][p16 * 64 + ((g4    ) ^ sw) * 8];
            pf1 = *(const bf16x8*)&Ps[w][p16 * 64 + ((g4 + 4) ^ sw) * 8];
        }
        #pragma unroll
        for (int nb = 0; nb < 4; ++nb) {
            int vrow = nb * 16 + p16;
            int sw = (vrow & 7) ^ ((vrow >> 3) & 7);
            bf16x8 vf0 = *(const bf16x8*)&Vt[cur][vrow * 64 + ((g4    ) ^ sw) * 8];
            bf16x8 vf1 = *(const bf16x8*)&Vt[cur][vrow * 64 + ((g4 + 4) ^ sw) * 8];
            o[nb] = MFMA16(pf0, vf0, o[nb]);
            o[nb] = MFMA16(pf1, vf1, o[nb]);
        }
        __syncthreads();
    }
#undef LOADV
#undef WRITEV
#undef STAGEK

    // --- epilogue ---
    #pragma unroll
    for (int r = 0; r < 4; ++r) {
        float t = lsum[r];
        t += __shfl_xor(t, 1); t += __shfl_xor(t, 2);
        t += __shfl_xor(t, 4); t += __shfl_xor(t, 8);
        lsum[r] = 1.f / t;
    }
    #pragma unroll
    for (int nb = 0; nb < 4; ++nb)
        #pragma unroll
        for (int r = 0; r < 4; ++r) {
            size_t gi = rowb + w * 16 + g4 * 4 + r;
            AO[gi * D_ + h * 64 + nb * 16 + p16] = (bf16_t)(o[nb][r] * lsum[r]);
        }
}

// ---------------------------------------------------------------------------
extern "C" void kernel_launch(void* const* d_in, const int* in_sizes, int n_in,
                              void* d_out, int out_size, void* d_ws, size_t ws_size,
                              hipStream_t stream) {
    const float* x    = (const float*)d_in[0];
    const float* Wq   = (const float*)d_in[1];
    const float* bq   = (const float*)d_in[2];
    const float* Wk   = (const float*)d_in[3];
    const float* bk   = (const float*)d_in[4];
    const float* Wv   = (const float*)d_in[5];
    const float* bv   = (const float*)d_in[6];
    const float* Wo   = (const float*)d_in[7];
    const float* bo   = (const float*)d_in[8];
    const float* relW = (const float*)d_in[9];
    const float* relB = (const float*)d_in[10];
    const float* lb   = (const float*)d_in[11];
    const float* gW   = (const float*)d_in[12];
    const float* gb   = (const float*)d_in[13];

    uint8_t* W8 = (uint8_t*)d_ws;
    bf16_t* xb  = (bf16_t*)(W8);
    bf16_t* wqb = (bf16_t*)(W8 + (8u  << 20));
    bf16_t* wkb = (bf16_t*)(W8 + (10u << 20));
    bf16_t* wvb = (bf16_t*)(W8 + (12u << 20));
    bf16_t* wob = (bf16_t*)(W8 + (14u << 20));
    bf16_t* Qb  = (bf16_t*)(W8 + (16u << 20));
    bf16_t* Kb  = (bf16_t*)(W8 + (24u << 20));
    bf16_t* Vb  = (bf16_t*)(W8 + (32u << 20));
    bf16_t* AOb = (bf16_t*)(W8 + (40u << 20));
    float*  EA  = (float*)(W8 + (48u << 20));
    float*  EB  = (float*)(W8 + (48u << 20) + 65536);
    float*  GAp = (float*)(W8 + (48u << 20) + 131072);

    cvt_all<<<8192, 256, 0, stream>>>(x, Wq, Wk, Wv, Wo, xb, wqb, wkb, wvb, wob);
    proj_small<<<NROW / 4, 256, 0, stream>>>(x, relW, relB, gW, gb, EA, EB, GAp);

    gemm_qkv<<<dim3(24, 32), 256, 0, stream>>>(xb, wqb, wkb, wvb, bq, bk, bv,
                                               Qb, Kb, Vb);

    flash_mfma<<<dim3(S_ / 64, B_ * H_), 256, 0, stream>>>(
        Qb, Kb, Vb, (const float4*)EA, (const float4*)EB, GAp, lb, AOb);

    gemm_out<<<dim3(8, 32), 256, 0, stream>>>(AOb, wob, bo, (float*)d_out);
}

// Round 7
// 270.004 us; speedup vs baseline: 5.3882x; 1.0428x over previous
//
#include <hip/hip_runtime.h>
#include <math.h>

#define B_   2
#define S_   2048
#define D_   1024
#define H_   16
#define NROW (B_ * S_)
#define L2E_ 1.4426950408889634f

typedef __bf16 bf16_t;
typedef __bf16 bf16x8 __attribute__((ext_vector_type(8)));
typedef __bf16 bf16x4v __attribute__((ext_vector_type(4)));
typedef float  f32x4  __attribute__((ext_vector_type(4)));
typedef unsigned u32x2 __attribute__((ext_vector_type(2)));
typedef unsigned u32x4 __attribute__((ext_vector_type(4)));

#define MFMA16(a, b, c) __builtin_amdgcn_mfma_f32_16x16x32_bf16((a), (b), (c), 0, 0, 0)

#if __has_builtin(__builtin_amdgcn_exp2f)
#define EXP2F(x) __builtin_amdgcn_exp2f(x)
#else
#define EXP2F(x) exp2f(x)
#endif

__device__ __forceinline__ void glds16(const void* src, void* lds) {
    __builtin_amdgcn_global_load_lds(
        (const __attribute__((address_space(1))) void*)src,
        (__attribute__((address_space(3))) void*)lds, 16, 0, 0);
}

// ---------------------------------------------------------------------------
// fp32 -> bf16 conversion for x and the 4 weight matrices.
// ---------------------------------------------------------------------------
__global__ __launch_bounds__(256)
void cvt_all(const float* __restrict__ x, const float* __restrict__ wq,
             const float* __restrict__ wk, const float* __restrict__ wv,
             const float* __restrict__ wo, bf16_t* __restrict__ xb,
             bf16_t* __restrict__ wqb, bf16_t* __restrict__ wkb,
             bf16_t* __restrict__ wvb, bf16_t* __restrict__ wob) {
    int bid = blockIdx.x;
    const float* src;
    bf16_t* dst;
    int base;
    if (bid < 4096) { src = x; dst = xb; base = bid; }
    else {
        int k = (bid - 4096) >> 10;
        base = (bid - 4096) & 1023;
        src = (k == 0) ? wq : (k == 1) ? wk : (k == 2) ? wv : wo;
        dst = (k == 0) ? wqb : (k == 1) ? wkb : (k == 2) ? wvb : wob;
    }
    int idx = base * 1024 + threadIdx.x * 4;
    float4 v = *(const float4*)&src[idx];
    bf16x4v o;
    o[0] = (bf16_t)v.x; o[1] = (bf16_t)v.y; o[2] = (bf16_t)v.z; o[3] = (bf16_t)v.w;
    *(bf16x4v*)&dst[idx] = o;
}

// ---------------------------------------------------------------------------
// Small projections -> EA4 (float4 exp(li+rb)), EBb (bf16x4 exp(lj), pad=0),
// GA (sigmoid gate). float4-vectorized loads.
// ---------------------------------------------------------------------------
__global__ __launch_bounds__(256)
void proj_small(const float* __restrict__ x, const float* __restrict__ relW,
                const float* __restrict__ relB, const float* __restrict__ gateW,
                const float* __restrict__ gateB,
                float* __restrict__ EA4, bf16_t* __restrict__ EBb,
                float* __restrict__ GA) {
    const int wave = threadIdx.x >> 6;
    const int lane = threadIdx.x & 63;
    const int row  = blockIdx.x * 4 + wave;

    const float4* xr = (const float4*)(x + (size_t)row * D_);
    float4 xv[4];
    #pragma unroll
    for (int t = 0; t < 4; ++t) xv[t] = xr[lane + 64 * t];

    for (int c = 0; c < 22; ++c) {
        const float* w;
        if (c < 3)       w = relW + c * (2 * D_);
        else if (c < 6)  w = relW + (c - 3) * (2 * D_) + D_;
        else             w = gateW + (size_t)(c - 6) * D_;
        const float4* w4 = (const float4*)w;
        float s = 0.f;
        #pragma unroll
        for (int t = 0; t < 4; ++t) {
            float4 wv = w4[lane + 64 * t];
            s += xv[t].x * wv.x + xv[t].y * wv.y + xv[t].z * wv.z + xv[t].w * wv.w;
        }
        #pragma unroll
        for (int off = 32; off; off >>= 1) s += __shfl_xor(s, off);
        if (lane == 0) {
            if (c < 3)      EA4[row * 4 + c] = expf(s + relB[c]);
            else if (c < 6) {
                EBb[row * 4 + (c - 3)] = (bf16_t)expf(s);
                if (c == 5) EBb[row * 4 + 3] = (bf16_t)0.f;
            } else          GA[row * H_ + (c - 6)] =
                                1.f / (1.f + expf(-(s + gateB[c - 6])));
        }
    }
}

// ---------------------------------------------------------------------------
// Shared 128x128 GEMM body, BK=64. Output address = i*csI + j*csJ (so the
// V projection can emit V^T [D][NROW] at identical cost).
// ---------------------------------------------------------------------------
__device__ __forceinline__ void gemm_body128(
    const bf16_t* __restrict__ A, const bf16_t* __restrict__ W,
    const float* __restrict__ bias, float scale, int row0, int col0,
    bf16_t* As, bf16_t* Bs, int outbf16, void* Cout,
    size_t csI, size_t csJ, int K)
{
    const int tid = threadIdx.x, w = tid >> 6, l = tid & 63;
    const int wr = w >> 1, wc = w & 1, p16 = l & 15, g4 = l >> 4;

    f32x4 acc[4][4];
    #pragma unroll
    for (int i = 0; i < 4; ++i)
        #pragma unroll
        for (int j = 0; j < 4; ++j) acc[i][j] = (f32x4){0.f, 0.f, 0.f, 0.f};

    const int sr = l >> 3, sc = l & 7;
    const bf16_t* aS = A + (size_t)(row0 + w * 32) * K;
    const bf16_t* bS = W + (size_t)(col0 + w * 32) * K;

    for (int k0 = 0; k0 < K; k0 += 64) {
        #pragma unroll
        for (int i = 0; i < 4; ++i) {
            int r = i * 8 + sr;
            int co = k0 + ((sc ^ sr) << 3);
            glds16(aS + (size_t)r * K + co, As + (w * 32 + i * 8) * 64);
            glds16(bS + (size_t)r * K + co, Bs + (w * 32 + i * 8) * 64);
        }
        __syncthreads();
        #pragma unroll
        for (int c = 0; c < 2; ++c) {
            bf16x8 af[4], bfr[4];
            #pragma unroll
            for (int mi = 0; mi < 4; ++mi) {
                int row = wr * 64 + mi * 16 + p16;
                af[mi] = *(const bf16x8*)&As[row * 64 + (((c * 4 + g4) ^ (row & 7)) << 3)];
            }
            #pragma unroll
            for (int nj = 0; nj < 4; ++nj) {
                int row = wc * 64 + nj * 16 + p16;
                bfr[nj] = *(const bf16x8*)&Bs[row * 64 + (((c * 4 + g4) ^ (row & 7)) << 3)];
            }
            #pragma unroll
            for (int mi = 0; mi < 4; ++mi)
                #pragma unroll
                for (int nj = 0; nj < 4; ++nj)
                    acc[mi][nj] = MFMA16(af[mi], bfr[nj], acc[mi][nj]);
        }
        __syncthreads();
    }

    const int cj = col0 + wc * 64 + p16;
    #pragma unroll
    for (int nj = 0; nj < 4; ++nj) {
        int j = cj + nj * 16;
        float bj = bias[j];
        #pragma unroll
        for (int mi = 0; mi < 4; ++mi) {
            int ib = row0 + wr * 64 + mi * 16 + g4 * 4;
            #pragma unroll
            for (int r = 0; r < 4; ++r) {
                float v = (acc[mi][nj][r] + bj) * scale;
                size_t addr = (size_t)(ib + r) * csI + (size_t)j * csJ;
                if (outbf16)
                    ((bf16_t*)Cout)[addr] = (bf16_t)v;
                else
                    ((float*)Cout)[addr] = v;
            }
        }
    }
}

// Merged Q/K/V projection. seg 0/1: normal [token][D]; seg 2 (V): V^T [D][NROW].
__global__ __launch_bounds__(256)
void gemm_qkv(const bf16_t* __restrict__ xb,
              const bf16_t* __restrict__ wq, const bf16_t* __restrict__ wk,
              const bf16_t* __restrict__ wv,
              const float* __restrict__ bq, const float* __restrict__ bk,
              const float* __restrict__ bv,
              bf16_t* __restrict__ Qb, bf16_t* __restrict__ Kb,
              bf16_t* __restrict__ Vtb) {
    __shared__ __align__(16) bf16_t As[128 * 64];
    __shared__ __align__(16) bf16_t Bs[128 * 64];
    const int seg = blockIdx.x >> 3;
    const int col0 = (blockIdx.x & 7) * 128;
    const int row0 = blockIdx.y * 128;
    const bf16_t* W = (seg == 0) ? wq : (seg == 1) ? wk : wv;
    const float* bias = (seg == 0) ? bq : (seg == 1) ? bk : bv;
    bf16_t* C = (seg == 0) ? Qb : (seg == 1) ? Kb : Vtb;
    const float scale = (seg == 0) ? 0.125f * L2E_ : 1.0f;
    const size_t csI = (seg == 2) ? 1 : (size_t)D_;
    const size_t csJ = (seg == 2) ? (size_t)NROW : 1;
    gemm_body128(xb, W, bias, scale, row0, col0, As, Bs, 1, C, csI, csJ, D_);
}

__global__ __launch_bounds__(256)
void gemm_out(const bf16_t* __restrict__ A, const bf16_t* __restrict__ wo,
              const float* __restrict__ bo, float* __restrict__ out) {
    __shared__ __align__(16) bf16_t As[128 * 64];
    __shared__ __align__(16) bf16_t Bs[128 * 64];
    gemm_body128(A, wo, bo, 1.0f, blockIdx.y * 128, blockIdx.x * 128,
                 As, Bs, 0, out, (size_t)D_, 1, D_);
}

// ---------------------------------------------------------------------------
// MFMA flash attention. K and V^T are both staged with glds16 into
// identically XOR-swizzled [row][chunk] LDS tiles (rows = j for K, d for V^T).
// No register V staging; eb row is a per-lane 8B L2 load.
// ---------------------------------------------------------------------------
__global__ __launch_bounds__(256, 4)
void flash_mfma(const bf16_t* __restrict__ Q, const bf16_t* __restrict__ Kg,
                const bf16_t* __restrict__ Vtg, const float4* __restrict__ EA4,
                const bf16_t* __restrict__ EBb, const float* __restrict__ GA,
                const float* __restrict__ LB, bf16_t* __restrict__ AO) {
    __shared__ __align__(16) bf16_t Ks[2][4096];   // K  [j][d-chunk swz]
    __shared__ __align__(16) bf16_t Vs[2][4096];   // V^T[d][j-chunk swz]
    __shared__ __align__(16) bf16_t Ps[4][1024];   // per-wave P [i][j] swz

    const int tid = threadIdx.x, w = tid >> 6, l = tid & 63;
    const int b = blockIdx.y >> 4, h = blockIdx.y & 15;
    const int i0 = blockIdx.x * 64;
    const size_t rowb = (size_t)b * S_ + i0;
    const int p16 = l & 15, g4 = l >> 4;

    const float lb0 = LB[h * 3 + 0], lb1 = LB[h * 3 + 1], lb2 = LB[h * 3 + 2];

    // Q A-fragments (registers for whole block)
    bf16x8 qf[2];
    {
        const bf16_t* qp = Q + (rowb + w * 16 + p16) * D_ + h * 64 + g4 * 8;
        qf[0] = *(const bf16x8*)qp;
        qf[1] = *(const bf16x8*)(qp + 32);
    }

    // Constant A-fragments for bias MFMAs
    bf16x8 zer;
    #pragma unroll
    for (int u = 0; u < 8; ++u) zer[u] = (bf16_t)0.f;
    bf16x8 cnf = zer, eaf = zer;
    {
        size_t gi = rowb + w * 16 + p16;
        float4 e = EA4[gi];
        float g = GA[gi * H_ + h] * L2E_;
        if (g4 == 0) {
            cnf[0] = (bf16_t)(g * e.x * lb0);
            cnf[1] = (bf16_t)(g * e.y * lb1);
            cnf[2] = (bf16_t)(g * e.z * lb2);
            eaf[0] = (bf16_t)e.x;
            eaf[1] = (bf16_t)e.y;
            eaf[2] = (bf16_t)e.z;
        }
    }

    // Staging pointers: lane (kr0, kc0); rows rowA/rowB within the 64-tile.
    const int kr0 = l >> 3, kc0 = l & 7;
    const int rowA = w * 16 + kr0, rowB = rowA + 8;
    const bf16_t* KpA = Kg + ((size_t)b * S_ + rowA) * D_ + h * 64 + ((kc0 ^ (rowA & 7)) << 3);
    const bf16_t* KpB = Kg + ((size_t)b * S_ + rowB) * D_ + h * 64 + ((kc0 ^ (rowB & 7)) << 3);
    const bf16_t* VpA = Vtg + (size_t)(h * 64 + rowA) * NROW + (size_t)b * S_ + ((kc0 ^ (rowA & 7)) << 3);
    const bf16_t* VpB = Vtg + (size_t)(h * 64 + rowB) * NROW + (size_t)b * S_ + ((kc0 ^ (rowB & 7)) << 3);

#define STAGE(buf, jt) do {                                                    \
        glds16(KpA + (size_t)(jt) * D_, &Ks[buf][w * 1024]);                   \
        glds16(KpB + (size_t)(jt) * D_, &Ks[buf][w * 1024 + 512]);             \
        glds16(VpA + (jt), &Vs[buf][w * 1024]);                                \
        glds16(VpB + (jt), &Vs[buf][w * 1024 + 512]);                          \
    } while (0)

    float lsum[4] = {0.f, 0.f, 0.f, 0.f};
    f32x4 o[4];
    #pragma unroll
    for (int nb = 0; nb < 4; ++nb) o[nb] = (f32x4){0.f, 0.f, 0.f, 0.f};

    STAGE(0, 0);
    __syncthreads();

    const bf16_t* ebbase = EBb + (size_t)b * S_ * 4;

    for (int t = 0; t < 32; ++t) {
        const int cur = t & 1;

        // eb row loads for this tile (8B each, L2-resident) — issue first
        u32x2 ebl[4];
        {
            const bf16_t* ebp = ebbase + (size_t)t * 64 * 4;
            #pragma unroll
            for (int nb = 0; nb < 4; ++nb)
                ebl[nb] = *(const u32x2*)&ebp[(nb * 16 + p16) * 4];
        }

        if (t < 31) STAGE(cur ^ 1, (t + 1) * 64);

        // --- QK^T ---
        f32x4 s[4];
        #pragma unroll
        for (int nb = 0; nb < 4; ++nb) {
            s[nb] = (f32x4){0.f, 0.f, 0.f, 0.f};
            int row = nb * 16 + p16;
            int sw = row & 7;
            bf16x8 k0v = *(const bf16x8*)&Ks[cur][row * 64 + ((g4    ) ^ sw) * 8];
            bf16x8 k1v = *(const bf16x8*)&Ks[cur][row * 64 + (((g4 + 4)) ^ sw) * 8];
            s[nb] = MFMA16(qf[0], k0v, s[nb]);
            s[nb] = MFMA16(qf[1], k1v, s[nb]);
        }

        // --- bias N/D via MFMA ---
        f32x4 nacc[4], dacc[4];
        #pragma unroll
        for (int nb = 0; nb < 4; ++nb) {
            u32x4 uu = {g4 == 0 ? ebl[nb][0] : 0u, g4 == 0 ? ebl[nb][1] : 0u, 0u, 0u};
            bf16x8 ebf = __builtin_bit_cast(bf16x8, uu);
            f32x4 z4 = (f32x4){0.f, 0.f, 0.f, 0.f};
            nacc[nb] = MFMA16(cnf, ebf, z4);
            dacc[nb] = MFMA16(eaf, ebf, z4);
        }

        // --- p = exp2(s + N/D); write P (per-wave LDS region) ---
        #pragma unroll
        for (int nb = 0; nb < 4; ++nb) {
            #pragma unroll
            for (int r = 0; r < 4; ++r) {
                float sv = s[nb][r] + nacc[nb][r] * __builtin_amdgcn_rcpf(dacc[nb][r]);
                float p = EXP2F(sv);
                bf16_t pb = (bf16_t)p;
                lsum[r] += (float)pb;
                int irow = g4 * 4 + r;
                int jcol = nb * 16 + p16;
                Ps[w][irow * 64 + (jcol ^ ((irow & 7) << 3))] = pb;
            }
        }

        // --- PV ---
        bf16x8 pf0, pf1;
        {
            int sw = p16 & 7;
            pf0 = *(const bf16x8*)&Ps[w][p16 * 64 + ((g4    ) ^ sw) * 8];
            pf1 = *(const bf16x8*)&Ps[w][p16 * 64 + ((g4 + 4) ^ sw) * 8];
        }
        #pragma unroll
        for (int nb = 0; nb < 4; ++nb) {
            int vrow = nb * 16 + p16;
            int sw = vrow & 7;
            bf16x8 vf0 = *(const bf16x8*)&Vs[cur][vrow * 64 + ((g4    ) ^ sw) * 8];
            bf16x8 vf1 = *(const bf16x8*)&Vs[cur][vrow * 64 + ((g4 + 4) ^ sw) * 8];
            o[nb] = MFMA16(pf0, vf0, o[nb]);
            o[nb] = MFMA16(pf1, vf1, o[nb]);
        }
        __syncthreads();
    }
#undef STAGE

    // --- epilogue ---
    #pragma unroll
    for (int r = 0; r < 4; ++r) {
        float t = lsum[r];
        t += __shfl_xor(t, 1); t += __shfl_xor(t, 2);
        t += __shfl_xor(t, 4); t += __shfl_xor(t, 8);
        lsum[r] = 1.f / t;
    }
    #pragma unroll
    for (int nb = 0; nb < 4; ++nb)
        #pragma unroll
        for (int r = 0; r < 4; ++r) {
            size_t gi = rowb + w * 16 + g4 * 4 + r;
            AO[gi * D_ + h * 64 + nb * 16 + p16] = (bf16_t)(o[nb][r] * lsum[r]);
        }
}

// ---------------------------------------------------------------------------
extern "C" void kernel_launch(void* const* d_in, const int* in_sizes, int n_in,
                              void* d_out, int out_size, void* d_ws, size_t ws_size,
                              hipStream_t stream) {
    const float* x    = (const float*)d_in[0];
    const float* Wq   = (const float*)d_in[1];
    const float* bq   = (const float*)d_in[2];
    const float* Wk   = (const float*)d_in[3];
    const float* bk   = (const float*)d_in[4];
    const float* Wv   = (const float*)d_in[5];
    const float* bv   = (const float*)d_in[6];
    const float* Wo   = (const float*)d_in[7];
    const float* bo   = (const float*)d_in[8];
    const float* relW = (const float*)d_in[9];
    const float* relB = (const float*)d_in[10];
    const float* lb   = (const float*)d_in[11];
    const float* gW   = (const float*)d_in[12];
    const float* gb   = (const float*)d_in[13];

    uint8_t* W8 = (uint8_t*)d_ws;
    bf16_t* xb  = (bf16_t*)(W8);
    bf16_t* wqb = (bf16_t*)(W8 + (8u  << 20));
    bf16_t* wkb = (bf16_t*)(W8 + (10u << 20));
    bf16_t* wvb = (bf16_t*)(W8 + (12u << 20));
    bf16_t* wob = (bf16_t*)(W8 + (14u << 20));
    bf16_t* Qb  = (bf16_t*)(W8 + (16u << 20));
    bf16_t* Kb  = (bf16_t*)(W8 + (24u << 20));
    bf16_t* Vtb = (bf16_t*)(W8 + (32u << 20));   // V^T [D][NROW]
    bf16_t* AOb = (bf16_t*)(W8 + (40u << 20));
    float*  EA  = (float*)(W8 + (48u << 20));
    bf16_t* EBb = (bf16_t*)(W8 + (48u << 20) + 65536);
    float*  GAp = (float*)(W8 + (48u << 20) + 98304);

    cvt_all<<<8192, 256, 0, stream>>>(x, Wq, Wk, Wv, Wo, xb, wqb, wkb, wvb, wob);
    proj_small<<<NROW / 4, 256, 0, stream>>>(x, relW, relB, gW, gb, EA, EBb, GAp);

    gemm_qkv<<<dim3(24, 32), 256, 0, stream>>>(xb, wqb, wkb, wvb, bq, bk, bv,
                                               Qb, Kb, Vtb);

    flash_mfma<<<dim3(S_ / 64, B_ * H_), 256, 0, stream>>>(
        Qb, Kb, Vtb, (const float4*)EA, EBb, GAp, lb, AOb);

    gemm_out<<<dim3(8, 32), 256, 0, stream>>>(AOb, wob, bo, (float*)d_out);
}